// Round 3
// baseline (2242.648 us; speedup 1.0000x reference)
//
#include <hip/hip_runtime.h>
#include <hip/hip_bf16.h>

// DTYPE GROUND TRUTH (round-3 theory): reference setup_inputs() returns fp32,
// harness passes fp32 -> cast d_in to const float*, write d_out as float.
// (Rounds 1-2 read fp32 as bf16 -> low mantissa bits form bf16-NaN patterns
// ~0.4%/elem -> NaN everywhere. Bounded math couldn't NaN on its own.)
typedef float f32;

// ---------------------------------------------------------------------------
// fp32 NT GEMM + bias: C[M,N] = A[M,K]*Bw[N,K]^T + bias[N].
// 64x64 block tile, BK=16, 256 threads, 4x4 micro-tile/thread.
// LDS stored transposed [k][m] so frags are contiguous float4 reads.
// ---------------------------------------------------------------------------
__global__ __launch_bounds__(256) void gemm_nt_bias_f32(
    const f32* __restrict__ A, const f32* __restrict__ Bw,
    const f32* __restrict__ bias, f32* __restrict__ C,
    int M, int N, int K)
{
    constexpr int BK = 16, LDM = 68;   // 68-float rows: 16B-aligned, bank-spread
    __shared__ f32 As[BK][LDM];        // [k][m]  4.4 KB
    __shared__ f32 Bs[BK][LDM];        // [k][n]

    const int tid = threadIdx.x;
    const int tx = tid & 15, ty = tid >> 4;          // 16x16 thread grid
    const size_t m0 = (size_t)blockIdx.y * 64;
    const size_t n0 = (size_t)blockIdx.x * 64;

    const int r  = tid >> 2;           // [0,64)  staging row
    const int kc = (tid & 3) * 4;      // {0,4,8,12}

    float acc[4][4] = {};

    for (int k0 = 0; k0 < K; k0 += BK) {
        float4 a4 = *(const float4*)&A [(m0 + r) * K + k0 + kc];
        float4 b4 = *(const float4*)&Bw[(n0 + r) * K + k0 + kc];

        __syncthreads();               // previous tile's frag reads done
        As[kc + 0][r] = a4.x; As[kc + 1][r] = a4.y;
        As[kc + 2][r] = a4.z; As[kc + 3][r] = a4.w;
        Bs[kc + 0][r] = b4.x; Bs[kc + 1][r] = b4.y;
        Bs[kc + 2][r] = b4.z; Bs[kc + 3][r] = b4.w;
        __syncthreads();

#pragma unroll
        for (int k = 0; k < BK; ++k) {
            float4 av = *(const float4*)&As[k][ty * 4];
            float4 bv = *(const float4*)&Bs[k][tx * 4];
            float a[4] = {av.x, av.y, av.z, av.w};
            float b[4] = {bv.x, bv.y, bv.z, bv.w};
#pragma unroll
            for (int i = 0; i < 4; ++i)
#pragma unroll
                for (int j = 0; j < 4; ++j)
                    acc[i][j] += a[i] * b[j];
        }
    }

#pragma unroll
    for (int i = 0; i < 4; ++i) {
        size_t row = m0 + ty * 4 + i;
#pragma unroll
        for (int j = 0; j < 4; ++j) {
            size_t col = n0 + tx * 4 + j;
            C[row * N + col] = acc[i][j] + bias[col];
        }
    }
}

// ---------------------------------------------------------------------------
// fp32 flash attention. 1 thread = 1 query; block = (b,h, 256 queries).
// K/V 64-key tiles staged in LDS; all lanes walk keys together (broadcast reads).
// Bounded online softmax: mask add -1e4 (exp underflows to exact 0), m init -1e5.
// qkv: [B*T, 3072] (q|k|v, each h*64+d). att out: [B*T, 1024].
// ---------------------------------------------------------------------------
__global__ __launch_bounds__(256) void attn_f32(
    const f32* __restrict__ qkv, const int* __restrict__ mask,
    f32* __restrict__ att, int B, int T)
{
    constexpr int D = 64, C3 = 3072, KT = 64, LDD = 68;
    __shared__ f32 Ks[KT][LDD];    // 17.4 KB
    __shared__ f32 Vs[KT][LDD];    // 17.4 KB
    __shared__ f32 madd[KT];

    const int tid = threadIdx.x;
    const int qc = blockIdx.x & 7;             // T/256 = 8 query chunks
    const int h  = (blockIdx.x >> 3) & 15;
    const int b  = blockIdx.x >> 7;
    const size_t base = (size_t)b * T;
    const int q = qc * 256 + tid;

    // load this thread's query vector
    float qv[D];
    {
        const f32* qp = &qkv[(base + q) * C3 + h * D];
#pragma unroll
        for (int dc = 0; dc < D / 4; ++dc) {
            float4 v = *(const float4*)&qp[dc * 4];
            qv[dc * 4 + 0] = v.x; qv[dc * 4 + 1] = v.y;
            qv[dc * 4 + 2] = v.z; qv[dc * 4 + 3] = v.w;
        }
    }

    float o[D];
#pragma unroll
    for (int d = 0; d < D; ++d) o[d] = 0.f;
    float m_run = -1e5f, l_run = 0.f;

    for (int kt = 0; kt < T / KT; ++kt) {
        __syncthreads();   // prev tile's reads done
        // stage K,V tiles: 64 keys x 64 d = 1024 float4 chunks each
#pragma unroll
        for (int i = 0; i < 4; ++i) {
            int cc = tid + i * 256;            // [0,1024)
            int rr = cc >> 4, dc = (cc & 15) * 4;
            const f32* kp = &qkv[(base + kt * KT + rr) * C3 + 1024 + h * D + dc];
            const f32* vp = &qkv[(base + kt * KT + rr) * C3 + 2048 + h * D + dc];
            *(float4*)&Ks[rr][dc] = *(const float4*)kp;
            *(float4*)&Vs[rr][dc] = *(const float4*)vp;
        }
        if (tid < KT)
            madd[tid] = (mask[base + kt * KT + tid] != 0) ? 0.f : -1e4f;
        __syncthreads();

        for (int kk = 0; kk < KT; ++kk) {
            float s0 = 0.f, s1 = 0.f, s2 = 0.f, s3 = 0.f;
#pragma unroll
            for (int dc = 0; dc < D / 4; ++dc) {
                float4 kv = *(const float4*)&Ks[kk][dc * 4];   // broadcast
                s0 += qv[dc * 4 + 0] * kv.x;
                s1 += qv[dc * 4 + 1] * kv.y;
                s2 += qv[dc * 4 + 2] * kv.z;
                s3 += qv[dc * 4 + 3] * kv.w;
            }
            float s = (s0 + s1 + s2 + s3) * 0.125f + madd[kk];
            if (s > m_run) {                    // rare rescale branch
                float a = __expf(m_run - s);
                m_run = s;
                l_run *= a;
#pragma unroll
                for (int d = 0; d < D; ++d) o[d] *= a;
            }
            float p = __expf(s - m_run);        // arg <= 0, underflows to 0 if masked
            l_run += p;
#pragma unroll
            for (int dc = 0; dc < D / 4; ++dc) {
                float4 vv = *(const float4*)&Vs[kk][dc * 4];   // broadcast
                o[dc * 4 + 0] += p * vv.x;
                o[dc * 4 + 1] += p * vv.y;
                o[dc * 4 + 2] += p * vv.z;
                o[dc * 4 + 3] += p * vv.w;
            }
        }
    }

    // l_run >= exp(0) = 1 at the global max (key 0 always valid), never 0
    float inv = 1.f / l_run;
    f32* op = &att[(base + q) * 1024 + h * D];
#pragma unroll
    for (int dc = 0; dc < D / 4; ++dc) {
        float4 v;
        v.x = o[dc * 4 + 0] * inv; v.y = o[dc * 4 + 1] * inv;
        v.z = o[dc * 4 + 2] * inv; v.w = o[dc * 4 + 3] * inv;
        *(float4*)&op[dc * 4] = v;
    }
}

// ---------------------------------------------------------------------------
extern "C" void kernel_launch(void* const* d_in, const int* in_sizes, int n_in,
                              void* d_out, int out_size, void* d_ws, size_t ws_size,
                              hipStream_t stream) {
    const f32* x     = (const f32*)d_in[0];   // [4,2048,1024] fp32
    const int* mask  = (const int*)d_in[1];   // [4,1,1,2048] int32
    const f32* qkv_w = (const f32*)d_in[2];   // [3072,1024]
    const f32* qkv_b = (const f32*)d_in[3];   // [3072]
    const f32* out_w = (const f32*)d_in[4];   // [1024,1024]
    const f32* out_b = (const f32*)d_in[5];   // [1024]
    f32* out = (f32*)d_out;                   // [4,2048,1024] fp32

    const int B = 4, T = 2048;
    const int M = B * T;                      // 8192
    f32* qkv = (f32*)d_ws;                    // [8192,3072] = 96 MB
    f32* att = qkv + (size_t)M * 3072;        // [8192,1024] = 32 MB

    dim3 blk(256);
    gemm_nt_bias_f32<<<dim3(3072 / 64, M / 64), blk, 0, stream>>>(x, qkv_w, qkv_b, qkv, M, 3072, 1024);
    attn_f32<<<dim3(B * 16 * (T / 256)), blk, 0, stream>>>(qkv, mask, att, B, T);
    gemm_nt_bias_f32<<<dim3(1024 / 64, M / 64), blk, 0, stream>>>(att, out_w, out_b, out, M, 1024, 1024);
}

// Round 4
// 646.690 us; speedup vs baseline: 3.4679x; 3.4679x over previous
//
#include <hip/hip_runtime.h>
#include <hip/hip_bf16.h>

// fp32 in / fp32 out (verified round 3). Internally: split-bf16 MFMA.
// x = hi + lo (bf16 each); A*B ~= Ah*Bh + Ah*Bl + Al*Bh  (fp32-grade, err ~2^-16)
typedef __bf16 bf16;
typedef __bf16 bf16x4_t __attribute__((ext_vector_type(4)));
typedef __bf16 bf16x8 __attribute__((ext_vector_type(8)));
typedef float f32x4 __attribute__((ext_vector_type(4)));

__device__ __forceinline__ void split8(float4 u, float4 v, bf16x8& hi, bf16x8& lo) {
    float f[8] = {u.x, u.y, u.z, u.w, v.x, v.y, v.z, v.w};
#pragma unroll
    for (int i = 0; i < 8; ++i) {
        bf16 h = (bf16)f[i];
        hi[i] = h;
        lo[i] = (bf16)(f[i] - (float)h);
    }
}

// ---------------------------------------------------------------------------
// Split-bf16 NT GEMM + bias: C[M,N] = A[M,K]*Bw[N,K]^T + bias[N], fp32 in/out.
// 128x128 tile, BK=32, 3-pass MFMA (hi*hi + hi*lo + lo*hi), fp32 accum.
// ---------------------------------------------------------------------------
__global__ __launch_bounds__(256) void gemm_nt_bias_split(
    const float* __restrict__ A, const float* __restrict__ Bw,
    const float* __restrict__ bias, float* __restrict__ C,
    int M, int N, int K)
{
    constexpr int BK = 32, LDK = 40;   // pad 32->40 elems (80 B rows)
    __shared__ bf16 Ah[128 * LDK], Al[128 * LDK];   // 10 KB each
    __shared__ bf16 Bh[128 * LDK], Bl[128 * LDK];   // 40 KB total

    const int tid  = threadIdx.x;
    const int lane = tid & 63, wave = tid >> 6;
    const int wy = wave >> 1, wx = wave & 1;        // 2x2 waves of 64x64
    const int lrow = lane & 15, quad = lane >> 4;
    const size_t m0 = (size_t)blockIdx.y * 128;
    const size_t n0 = (size_t)blockIdx.x * 128;
    const int r0 = tid >> 2;            // [0,64)
    const int kc = (tid & 3) * 8;       // {0,8,16,24}

    f32x4 acc[4][4] = {};

    for (int k0 = 0; k0 < K; k0 += BK) {
        const float* pa = &A [(m0 + r0) * K + k0 + kc];
        const float* pb = &Bw[(n0 + r0) * K + k0 + kc];
        float4 a00 = *(const float4*)pa;
        float4 a01 = *(const float4*)(pa + 4);
        float4 a10 = *(const float4*)(pa + (size_t)64 * K);
        float4 a11 = *(const float4*)(pa + (size_t)64 * K + 4);
        float4 b00 = *(const float4*)pb;
        float4 b01 = *(const float4*)(pb + 4);
        float4 b10 = *(const float4*)(pb + (size_t)64 * K);
        float4 b11 = *(const float4*)(pb + (size_t)64 * K + 4);

        __syncthreads();   // prev iteration's frag reads complete
        bf16x8 h, l;
        split8(a00, a01, h, l); *(bf16x8*)&Ah[ r0       * LDK + kc] = h; *(bf16x8*)&Al[ r0       * LDK + kc] = l;
        split8(a10, a11, h, l); *(bf16x8*)&Ah[(r0 + 64) * LDK + kc] = h; *(bf16x8*)&Al[(r0 + 64) * LDK + kc] = l;
        split8(b00, b01, h, l); *(bf16x8*)&Bh[ r0       * LDK + kc] = h; *(bf16x8*)&Bl[ r0       * LDK + kc] = l;
        split8(b10, b11, h, l); *(bf16x8*)&Bh[(r0 + 64) * LDK + kc] = h; *(bf16x8*)&Bl[(r0 + 64) * LDK + kc] = l;
        __syncthreads();

        bf16x8 ah[4], al[4], bh[4], bl[4];
#pragma unroll
        for (int i = 0; i < 4; ++i) {
            ah[i] = *(const bf16x8*)&Ah[(wy * 64 + i * 16 + lrow) * LDK + quad * 8];
            al[i] = *(const bf16x8*)&Al[(wy * 64 + i * 16 + lrow) * LDK + quad * 8];
        }
#pragma unroll
        for (int j = 0; j < 4; ++j) {
            bh[j] = *(const bf16x8*)&Bh[(wx * 64 + j * 16 + lrow) * LDK + quad * 8];
            bl[j] = *(const bf16x8*)&Bl[(wx * 64 + j * 16 + lrow) * LDK + quad * 8];
        }
#pragma unroll
        for (int i = 0; i < 4; ++i)
#pragma unroll
            for (int j = 0; j < 4; ++j) {
                acc[i][j] = __builtin_amdgcn_mfma_f32_16x16x32_bf16(ah[i], bh[j], acc[i][j], 0, 0, 0);
                acc[i][j] = __builtin_amdgcn_mfma_f32_16x16x32_bf16(ah[i], bl[j], acc[i][j], 0, 0, 0);
                acc[i][j] = __builtin_amdgcn_mfma_f32_16x16x32_bf16(al[i], bh[j], acc[i][j], 0, 0, 0);
            }
    }

    // C/D layout: col=lane&15, row=quad*4+reg  [m89/m91]
#pragma unroll
    for (int i = 0; i < 4; ++i) {
        size_t row = m0 + wy * 64 + i * 16 + quad * 4;
#pragma unroll
        for (int j = 0; j < 4; ++j) {
            size_t col = n0 + wx * 64 + j * 16 + lrow;
            float bb = bias[col];
#pragma unroll
            for (int r = 0; r < 4; ++r)
                C[(row + r) * N + col] = acc[i][j][r] + bb;
        }
    }
}

// ---------------------------------------------------------------------------
// Flash attention, MFMA. Block = (b,h, 128 queries); 64-key tiles.
// QK^T in split-bf16 (3 passes, scores fp32-grade); P,V plain bf16 (errors
// suppressed by softmax averaging). qkv fp32 [B*T,3072]; att fp32 [B*T,1024].
// ---------------------------------------------------------------------------
__global__ __launch_bounds__(256) void attn_mfma(
    const float* __restrict__ qkv, const int* __restrict__ mask,
    float* __restrict__ att, int B, int T)
{
    constexpr int C3 = 3072, QT = 128, KT = 64, LD = 72;
    __shared__ bf16 Khi[KT * LD], Klo[KT * LD];   // 9 KB each
    __shared__ bf16 Vt[64 * LD];                  // [d][key] 9 KB
    __shared__ bf16 Ps[QT * LD];                  // 18 KB (also Q staging)
    __shared__ float smadd[KT];

    const int tid  = threadIdx.x;
    const int lane = tid & 63;
    const int wave = tid >> 6;      // wave owns query rows [wave*32, wave*32+32)
    const int lrow = lane & 15, quad = lane >> 4;

    const int qt = blockIdx.x & 15;           // T/128 = 16
    const int h  = (blockIdx.x >> 4) & 15;
    const int b  = blockIdx.x >> 8;
    const size_t base = (size_t)b * T;

    // ---- stage Q (fp32), split, frag-load via Ps round-trips ----
    bf16x8 aqh[2][2], aql[2][2];
    {
        const int r = tid >> 1, c0 = (tid & 1) * 32;   // 128 rows x 64 cols
        const float* qp = &qkv[(base + qt * QT + r) * C3 + h * 64 + c0];
        bf16x8 qh[4], ql[4];
#pragma unroll
        for (int t = 0; t < 4; ++t) {
            float4 u = *(const float4*)(qp + t * 8);
            float4 v = *(const float4*)(qp + t * 8 + 4);
            split8(u, v, qh[t], ql[t]);
        }
#pragma unroll
        for (int t = 0; t < 4; ++t) *(bf16x8*)&Ps[r * LD + c0 + t * 8] = qh[t];
        __syncthreads();
#pragma unroll
        for (int qi = 0; qi < 2; ++qi)
#pragma unroll
            for (int ks = 0; ks < 2; ++ks)
                aqh[qi][ks] = *(const bf16x8*)&Ps[(wave * 32 + qi * 16 + lrow) * LD + ks * 32 + quad * 8];
        __syncthreads();
#pragma unroll
        for (int t = 0; t < 4; ++t) *(bf16x8*)&Ps[r * LD + c0 + t * 8] = ql[t];
        __syncthreads();
#pragma unroll
        for (int qi = 0; qi < 2; ++qi)
#pragma unroll
            for (int ks = 0; ks < 2; ++ks)
                aql[qi][ks] = *(const bf16x8*)&Ps[(wave * 32 + qi * 16 + lrow) * LD + ks * 32 + quad * 8];
    }

    f32x4 oacc[2][4] = {};
    float m_run[2][4], l_run[2][4];
#pragma unroll
    for (int qi = 0; qi < 2; ++qi)
#pragma unroll
        for (int r = 0; r < 4; ++r) { m_run[qi][r] = -1e5f; l_run[qi][r] = 0.f; }

    for (int kt = 0; kt < T / KT; ++kt) {
        __syncthreads();   // prev iter frag reads (and Q phase) complete
        // ---- stage K (split) + V (transposed bf16): 64 keys x 64 d ----
#pragma unroll
        for (int i = 0; i < 4; ++i) {
            int c = tid + i * 256;             // [0,1024)
            int rr = c >> 4, dc = (c & 15) * 4;
            const float* kp = &qkv[(base + kt * KT + rr) * C3 + 1024 + h * 64 + dc];
            const float* vp = &qkv[(base + kt * KT + rr) * C3 + 2048 + h * 64 + dc];
            float4 kf = *(const float4*)kp;
            float4 vf = *(const float4*)vp;
            bf16x4_t kh, kl;
            float k4[4] = {kf.x, kf.y, kf.z, kf.w};
#pragma unroll
            for (int u = 0; u < 4; ++u) {
                bf16 hh = (bf16)k4[u];
                kh[u] = hh;
                kl[u] = (bf16)(k4[u] - (float)hh);
            }
            *(bf16x4_t*)&Khi[rr * LD + dc] = kh;
            *(bf16x4_t*)&Klo[rr * LD + dc] = kl;
            float v4[4] = {vf.x, vf.y, vf.z, vf.w};
#pragma unroll
            for (int u = 0; u < 4; ++u)
                Vt[(dc + u) * LD + rr] = (bf16)v4[u];
        }
        if (tid < KT) smadd[tid] = (mask[base + kt * KT + tid] != 0) ? 0.f : -1e4f;
        __syncthreads();

        // ---- S = Q K^T, split 3-pass ----
        bf16x8 bkh[4][2], bkl[4][2];
#pragma unroll
        for (int ni = 0; ni < 4; ++ni)
#pragma unroll
            for (int ks = 0; ks < 2; ++ks) {
                bkh[ni][ks] = *(const bf16x8*)&Khi[(ni * 16 + lrow) * LD + ks * 32 + quad * 8];
                bkl[ni][ks] = *(const bf16x8*)&Klo[(ni * 16 + lrow) * LD + ks * 32 + quad * 8];
            }
        f32x4 s[2][4];
#pragma unroll
        for (int qi = 0; qi < 2; ++qi)
#pragma unroll
            for (int ni = 0; ni < 4; ++ni) {
                f32x4 t = {0.f, 0.f, 0.f, 0.f};
                t = __builtin_amdgcn_mfma_f32_16x16x32_bf16(aqh[qi][0], bkh[ni][0], t, 0, 0, 0);
                t = __builtin_amdgcn_mfma_f32_16x16x32_bf16(aqh[qi][1], bkh[ni][1], t, 0, 0, 0);
                t = __builtin_amdgcn_mfma_f32_16x16x32_bf16(aql[qi][0], bkh[ni][0], t, 0, 0, 0);
                t = __builtin_amdgcn_mfma_f32_16x16x32_bf16(aql[qi][1], bkh[ni][1], t, 0, 0, 0);
                t = __builtin_amdgcn_mfma_f32_16x16x32_bf16(aqh[qi][0], bkl[ni][0], t, 0, 0, 0);
                t = __builtin_amdgcn_mfma_f32_16x16x32_bf16(aqh[qi][1], bkl[ni][1], t, 0, 0, 0);
                s[qi][ni] = t;
            }

        // ---- scale + mask + online softmax (rows live in 16-lane quads) ----
        float madd[4];
#pragma unroll
        for (int ni = 0; ni < 4; ++ni) madd[ni] = smadd[ni * 16 + lrow];
#pragma unroll
        for (int qi = 0; qi < 2; ++qi)
#pragma unroll
            for (int ni = 0; ni < 4; ++ni)
#pragma unroll
                for (int r = 0; r < 4; ++r)
                    s[qi][ni][r] = s[qi][ni][r] * 0.125f + madd[ni];

        float alpha[2][4];
#pragma unroll
        for (int qi = 0; qi < 2; ++qi)
#pragma unroll
            for (int r = 0; r < 4; ++r) {
                float mx = fmaxf(fmaxf(s[qi][0][r], s[qi][1][r]), fmaxf(s[qi][2][r], s[qi][3][r]));
#pragma unroll
                for (int off = 1; off < 16; off <<= 1) mx = fmaxf(mx, __shfl_xor(mx, off));
                float mn = fmaxf(m_run[qi][r], mx);
                float a  = __expf(m_run[qi][r] - mn);
                float rs = 0.f;
#pragma unroll
                for (int ni = 0; ni < 4; ++ni) {
                    float e = __expf(s[qi][ni][r] - mn);
                    s[qi][ni][r] = e;
                    rs += e;
                }
#pragma unroll
                for (int off = 1; off < 16; off <<= 1) rs += __shfl_xor(rs, off);
                m_run[qi][r] = mn;
                l_run[qi][r] = l_run[qi][r] * a + rs;
                alpha[qi][r] = a;
            }
#pragma unroll
        for (int qi = 0; qi < 2; ++qi)
#pragma unroll
            for (int di = 0; di < 4; ++di)
#pragma unroll
                for (int r = 0; r < 4; ++r)
                    oacc[qi][di][r] *= alpha[qi][r];

        // ---- P (C-layout) -> LDS (own wave's rows) ----
#pragma unroll
        for (int qi = 0; qi < 2; ++qi)
#pragma unroll
            for (int ni = 0; ni < 4; ++ni)
#pragma unroll
                for (int r = 0; r < 4; ++r)
                    Ps[(wave * 32 + qi * 16 + quad * 4 + r) * LD + ni * 16 + lrow] = (bf16)s[qi][ni][r];
        __syncthreads();

        // ---- O += P V ----
        bf16x8 bv[4][2];
#pragma unroll
        for (int di = 0; di < 4; ++di)
#pragma unroll
            for (int ks = 0; ks < 2; ++ks)
                bv[di][ks] = *(const bf16x8*)&Vt[(di * 16 + lrow) * LD + ks * 32 + quad * 8];
#pragma unroll
        for (int qi = 0; qi < 2; ++qi) {
            bf16x8 ap0 = *(const bf16x8*)&Ps[(wave * 32 + qi * 16 + lrow) * LD + quad * 8];
            bf16x8 ap1 = *(const bf16x8*)&Ps[(wave * 32 + qi * 16 + lrow) * LD + 32 + quad * 8];
#pragma unroll
            for (int di = 0; di < 4; ++di) {
                oacc[qi][di] = __builtin_amdgcn_mfma_f32_16x16x32_bf16(ap0, bv[di][0], oacc[qi][di], 0, 0, 0);
                oacc[qi][di] = __builtin_amdgcn_mfma_f32_16x16x32_bf16(ap1, bv[di][1], oacc[qi][di], 0, 0, 0);
            }
        }
    }

    // ---- epilogue: O/l -> att fp32 ----
#pragma unroll
    for (int qi = 0; qi < 2; ++qi)
#pragma unroll
        for (int r = 0; r < 4; ++r) {
            float inv = 1.f / l_run[qi][r];   // >= 1: key 0 always valid
            int q = qt * QT + wave * 32 + qi * 16 + quad * 4 + r;
#pragma unroll
            for (int di = 0; di < 4; ++di)
                att[(base + q) * 1024 + h * 64 + di * 16 + lrow] = oacc[qi][di][r] * inv;
        }
}

// ---------------------------------------------------------------------------
extern "C" void kernel_launch(void* const* d_in, const int* in_sizes, int n_in,
                              void* d_out, int out_size, void* d_ws, size_t ws_size,
                              hipStream_t stream) {
    const float* x     = (const float*)d_in[0];   // [4,2048,1024]
    const int*   mask  = (const int*)d_in[1];     // [4,1,1,2048]
    const float* qkv_w = (const float*)d_in[2];   // [3072,1024]
    const float* qkv_b = (const float*)d_in[3];   // [3072]
    const float* out_w = (const float*)d_in[4];   // [1024,1024]
    const float* out_b = (const float*)d_in[5];   // [1024]
    float* out = (float*)d_out;                   // [4,2048,1024]

    const int B = 4, T = 2048;
    const int M = B * T;                          // 8192
    float* qkv = (float*)d_ws;                    // [8192,3072] = 96 MB
    float* att = qkv + (size_t)M * 3072;          // [8192,1024] = 32 MB

    dim3 blk(256);
    gemm_nt_bias_split<<<dim3(3072 / 128, M / 128), blk, 0, stream>>>(x, qkv_w, qkv_b, qkv, M, 3072, 1024);
    attn_mfma<<<dim3(B * 16 * (T / 128)), blk, 0, stream>>>(qkv, mask, att, B, T);
    gemm_nt_bias_split<<<dim3(1024 / 128, M / 128), blk, 0, stream>>>(att, out_w, out_b, out, M, 1024, 1024);
}